// Round 7
// baseline (677.942 us; speedup 1.0000x reference)
//
#include <hip/hip_runtime.h>

#define VOCABSZ 256
#define EMBED   32
#define HIDDEN  32
#define LAYERS  10
#define BATCH   1024
#define SEQ     1024
#define BPB     16      // batch elems per block (= MFMA N)
#define U       8       // timesteps per wave per barrier interval
#define NBODY   (SEQ / U + LAYERS)   // 138 bodies (even); last body inactive

typedef _Float16 f16x8 __attribute__((ext_vector_type(8)));
typedef float    f32x4 __attribute__((ext_vector_type(4)));
typedef _Float16 h2    __attribute__((ext_vector_type(2)));

__device__ __forceinline__ unsigned pk(float a, float b) {
    h2 t; t[0] = (_Float16)a; t[1] = (_Float16)b;
    return __builtin_bit_cast(unsigned, t);
}
__device__ __forceinline__ f16x8 u2f(uint4 u) { return __builtin_bit_cast(f16x8, u); }

// tanh(c + bias) with bias prefolded: t = c*2log2e + bias2; 1 - 2/(1+2^t).
__device__ __forceinline__ float th(float c, float b2) {
    const float t = __builtin_fmaf(c, 2.8853900817779268f, b2);
#if __has_builtin(__builtin_amdgcn_exp2f)
    const float e = __builtin_amdgcn_exp2f(t);
#else
    const float e = __expf(0.6931471805599453f * t);
#endif
    const float r = __builtin_amdgcn_rcpf(1.0f + e);
    return __builtin_fmaf(-2.0f, r, 1.0f);
}

// A-fragment builders (lane (bc,g) takes 8 cols of its weight row, f16).
// natural: cols 8g..8g+7.  kperm: cols {4g..4g+3, 16+4g..16+4g+3} — the kappa
// ordering that makes C-fragment outputs land in-lane as the next B-frag.
__device__ __forceinline__ uint4 mk_nat(const float* row, int g) {
    const float4 a = *(const float4*)(row + 8 * g);
    const float4 b = *(const float4*)(row + 8 * g + 4);
    return uint4{pk(a.x, a.y), pk(a.z, a.w), pk(b.x, b.y), pk(b.z, b.w)};
}
__device__ __forceinline__ uint4 mk_kp(const float* row, int g) {
    const float4 a = *(const float4*)(row + 4 * g);
    const float4 b = *(const float4*)(row + 16 + 4 * g);
    return uint4{pk(a.x, a.y), pk(a.z, a.w), pk(b.x, b.y), pk(b.z, b.w)};
}

// Persistent skewed layer-pipeline, U=8, fused FC epilogue.
// Block = 16 batch, 640 thr = 10 waves, wave w owns layer w.
// Recurrence fully in-register (kappa trick, verified rounds 3-6).
// Cross-layer handoff: one ds_write_b128 / ds_read_b128 per (w,u).
// FC: wave 9's final bown IS h_T's B-fragment; W_fc rows mk_kp-packed.
__global__ __launch_bounds__(640, 1) void rnn_fused(
    const int* __restrict__ x, const float* __restrict__ emb,
    const float* __restrict__ W_ih, const float* __restrict__ W_hh,
    const float* __restrict__ b_ih, const float* __restrict__ b_hh,
    const float* __restrict__ W_fc, const float* __restrict__ b_fc,
    float* __restrict__ out)
{
    __shared__ __align__(16) unsigned char hb[2 * (LAYERS - 1) * U * 1024]; // 144 KB
    __shared__ __align__(16) unsigned char fcs[1024];                       // h_T frag

    const int tid   = threadIdx.x;
    const int w     = tid >> 6;       // wave == layer
    const int lane  = tid & 63;
    const int bc    = lane & 15;      // batch col
    const int g     = lane >> 4;      // k-group / C row-group
    const int bbase = blockIdx.x * BPB;

    // zero h slots (h0 = 0; one-time insurance against poison)
    for (int i = tid; i < (int)sizeof(hb) / 4; i += 640)
        ((unsigned*)hb)[i] = 0u;

    // ---- weight A-fragments (kappa-permuted cols; layer-0 W_ih natural)
    const float* ri0 = W_ih + (w * HIDDEN + bc)      * EMBED;
    const float* ri1 = W_ih + (w * HIDDEN + 16 + bc) * EMBED;
    const float* rh0 = W_hh + (w * HIDDEN + bc)      * HIDDEN;
    const float* rh1 = W_hh + (w * HIDDEN + 16 + bc) * HIDDEN;
    const uint4 wf00 = (w == 0) ? mk_nat(ri0, g) : mk_kp(ri0, g);
    const uint4 wf10 = (w == 0) ? mk_nat(ri1, g) : mk_kp(ri1, g);
    const uint4 wf01 = mk_kp(rh0, g);
    const uint4 wf11 = mk_kp(rh1, g);

    float bias2[8];
    #pragma unroll
    for (int m = 0; m < 2; ++m)
        #pragma unroll
        for (int r = 0; r < 4; ++r) {
            const int hid = w * HIDDEN + m * 16 + g * 4 + r;
            bias2[m * 4 + r] = 2.8853900817779268f * (b_ih[hid] + b_hh[hid]);
        }

    #define SL(p, l, u_) ((((p) * (LAYERS - 1) + (l)) * U + (u_)) * 1024)
    const int off = g * 256 + bc * 16;   // b128 frag address (write == read image)

    // ---- wave-0 feeder: cur = input frags for this iter; tokens 1 iter ahead
    uint4  cur[U];
    float4 eraw[U][2];
    int    tokpf[U];
    const int* xp = x + (bbase + bc) * SEQ;
    if (w == 0) {
        const int4 a = *(const int4*)(xp), b = *(const int4*)(xp + 4);
        const int tk[U] = {a.x, a.y, a.z, a.w, b.x, b.y, b.z, b.w};
        #pragma unroll
        for (int u = 0; u < U; ++u) {
            const float4* ep = (const float4*)(emb + tk[u] * EMBED + g * 8);
            const float4 e0 = ep[0], e1 = ep[1];
            cur[u] = uint4{pk(e0.x, e0.y), pk(e0.z, e0.w), pk(e1.x, e1.y), pk(e1.z, e1.w)};
        }
        const int4 c = *(const int4*)(xp + 8), d = *(const int4*)(xp + 12);
        tokpf[0] = c.x; tokpf[1] = c.y; tokpf[2] = c.z; tokpf[3] = c.w;
        tokpf[4] = d.x; tokpf[5] = d.y; tokpf[6] = d.z; tokpf[7] = d.w;
    }

    uint4 bown = uint4{0, 0, 0, 0};   // own-h B-frag, register-resident forever
    const f32x4 z = {0.f, 0.f, 0.f, 0.f};

    auto body = [&](int it, int P) {
        __syncthreads();                       // one barrier per U=8 timesteps
        const int tb = (it - w) * U;
        if (tb < 0 || tb >= SEQ) return;       // wave-uniform

        // feeder: issue next-iter emb gathers (tokens prefetched last iter)
        const bool pf = (w == 0) && (tb + U < SEQ);
        if (pf) {
            #pragma unroll
            for (int u = 0; u < U; ++u) {
                const float4* ep = (const float4*)(emb + tokpf[u] * EMBED + g * 8);
                eraw[u][0] = ep[0]; eraw[u][1] = ep[1];
            }
            if (tb + 2 * U < SEQ) {
                const int4 c = *(const int4*)(xp + tb + 2 * U);
                const int4 d = *(const int4*)(xp + tb + 2 * U + 4);
                tokpf[0] = c.x; tokpf[1] = c.y; tokpf[2] = c.z; tokpf[3] = c.w;
                tokpf[4] = d.x; tokpf[5] = d.y; tokpf[6] = d.z; tokpf[7] = d.w;
            }
        }

        // input fragments + batched input MFMAs (off the serial chain)
        uint4 bin[U];
        if (w == 0) {
            #pragma unroll
            for (int u = 0; u < U; ++u) bin[u] = cur[u];
        } else {
            #pragma unroll
            for (int u = 0; u < U; ++u)
                bin[u] = *(const uint4*)(hb + SL(P ^ 1, w - 1, u) + off);
        }
        f32x4 cin0[U], cin1[U];
        #pragma unroll
        for (int u = 0; u < U; ++u) {
            cin0[u] = __builtin_amdgcn_mfma_f32_16x16x32_f16(u2f(wf00), u2f(bin[u]), z, 0, 0, 0);
            cin1[u] = __builtin_amdgcn_mfma_f32_16x16x32_f16(u2f(wf10), u2f(bin[u]), z, 0, 0, 0);
        }

        // serial recurrence: mfma -> tanh -> pack IS the next B-frag (in-lane)
        #pragma unroll
        for (int u = 0; u < U; ++u) {
            const f32x4 c0 = __builtin_amdgcn_mfma_f32_16x16x32_f16(u2f(wf01), u2f(bown), cin0[u], 0, 0, 0);
            const f32x4 c1 = __builtin_amdgcn_mfma_f32_16x16x32_f16(u2f(wf11), u2f(bown), cin1[u], 0, 0, 0);

            float hv[8];
            #pragma unroll
            for (int r = 0; r < 4; ++r) {
                hv[r]     = th(c0[r], bias2[r]);
                hv[4 + r] = th(c1[r], bias2[4 + r]);
            }
            bown = uint4{pk(hv[0], hv[1]), pk(hv[2], hv[3]),
                         pk(hv[4], hv[5]), pk(hv[6], hv[7])};

            if (w < LAYERS - 1)   // handoff for next layer (one b128)
                *(uint4*)(hb + SL(P, w, u) + off) = bown;
        }

        if (pf) {   // pack next-iter input frags (emb loads spanned the body)
            #pragma unroll
            for (int u = 0; u < U; ++u) {
                const float4 e0 = eraw[u][0], e1 = eraw[u][1];
                cur[u] = uint4{pk(e0.x, e0.y), pk(e0.z, e0.w), pk(e1.x, e1.y), pk(e1.z, e1.w)};
            }
        }
    };

    for (int it = 0; it < NBODY; it += 2) {   // parity static per body
        body(it, 0);
        body(it + 1, 1);
    }
    #undef SL

    // ---- fused FC epilogue: out[b][v] = h_T . W_fc[v] + b_fc[v]
    // wave 9's bown == h_T B-fragment (same image every consumer used all run)
    if (w == LAYERS - 1) *(uint4*)(fcs + off) = bown;
    __syncthreads();
    const uint4 bfc = *(const uint4*)(fcs + off);
    #pragma unroll
    for (int rep = 0; rep < 2; ++rep) {
        const int vt = w + rep * LAYERS;      // vocab tile 0..15
        if (vt < VOCABSZ / 16) {
            const uint4 afc = mk_kp(W_fc + (vt * 16 + bc) * HIDDEN, g);
            const f32x4 c = __builtin_amdgcn_mfma_f32_16x16x32_f16(u2f(afc), u2f(bfc), z, 0, 0, 0);
            const float4 b4 = *(const float4*)(b_fc + vt * 16 + 4 * g);
            const float4 o  = {c[0] + b4.x, c[1] + b4.y, c[2] + b4.z, c[3] + b4.w};
            *(float4*)(out + (bbase + bc) * VOCABSZ + vt * 16 + 4 * g) = o;
        }
    }
}

extern "C" void kernel_launch(void* const* d_in, const int* in_sizes, int n_in,
                              void* d_out, int out_size, void* d_ws, size_t ws_size,
                              hipStream_t stream) {
    const int*   x    = (const int*)d_in[0];
    const float* emb  = (const float*)d_in[1];
    const float* W_ih = (const float*)d_in[2];
    const float* W_hh = (const float*)d_in[3];
    const float* b_ih = (const float*)d_in[4];
    const float* b_hh = (const float*)d_in[5];
    const float* W_fc = (const float*)d_in[6];
    const float* b_fc = (const float*)d_in[7];
    float* out = (float*)d_out;

    rnn_fused<<<BATCH / BPB, 640, 0, stream>>>(x, emb, W_ih, W_hh, b_ih, b_hh,
                                               W_fc, b_fc, out);
}

// Round 8
// 559.266 us; speedup vs baseline: 1.2122x; 1.2122x over previous
//
#include <hip/hip_runtime.h>

#define VOCABSZ 256
#define EMBED   32
#define HIDDEN  32
#define LAYERS  10
#define BATCH   1024
#define SEQ     1024
#define BPB     16      // batch elems per block (= MFMA N)
#define U       4       // timesteps per body (U=8 spilled: round-7 WRITE_SIZE 9.3MB)
#define DEPTH   4       // h-slot ring depth: >=3 gives waves drift slack (phase mixing)
#define NB      268     // bodies, padded to multiple of 4 (265 needed; tail inactive)

typedef _Float16 f16x8 __attribute__((ext_vector_type(8)));
typedef float    f32x4 __attribute__((ext_vector_type(4)));
typedef _Float16 h2    __attribute__((ext_vector_type(2)));

__device__ __forceinline__ unsigned pk(float a, float b) {
    h2 t; t[0] = (_Float16)a; t[1] = (_Float16)b;
    return __builtin_bit_cast(unsigned, t);
}
__device__ __forceinline__ f16x8 u2f(uint4 u) { return __builtin_bit_cast(f16x8, u); }

// tanh(c + bias) with bias prefolded: t = c*2log2e + bias2; 1 - 2/(1+2^t).
__device__ __forceinline__ float th(float c, float b2) {
    const float t = __builtin_fmaf(c, 2.8853900817779268f, b2);
#if __has_builtin(__builtin_amdgcn_exp2f)
    const float e = __builtin_amdgcn_exp2f(t);
#else
    const float e = __expf(0.6931471805599453f * t);
#endif
    const float r = __builtin_amdgcn_rcpf(1.0f + e);
    return __builtin_fmaf(-2.0f, r, 1.0f);
}

// A-fragment builders (lane (bc,g) takes 8 cols of its weight row, f16).
// natural: cols 8g..8g+7.  kperm: cols {4g..4g+3, 16+4g..16+4g+3} — the kappa
// ordering that makes C-fragment outputs land in-lane as the next B-frag.
__device__ __forceinline__ uint4 mk_nat(const float* row, int g) {
    const float4 a = *(const float4*)(row + 8 * g);
    const float4 b = *(const float4*)(row + 8 * g + 4);
    return uint4{pk(a.x, a.y), pk(a.z, a.w), pk(b.x, b.y), pk(b.z, b.w)};
}
__device__ __forceinline__ uint4 mk_kp(const float* row, int g) {
    const float4 a = *(const float4*)(row + 4 * g);
    const float4 b = *(const float4*)(row + 16 + 4 * g);
    return uint4{pk(a.x, a.y), pk(a.z, a.w), pk(b.x, b.y), pk(b.z, b.w)};
}

// Free-running systolic layer pipeline (NO barrier in the main loop).
// Block = 16 batch, 640 thr = 10 waves, wave w owns layer w.
// Sync: per-wave progress flags in LDS. Wave w before body `it` requires
//   prog[w-1] >= it      (producer wrote body it-1's slots = our inputs)
//   prog[w+1] >= it-2    (consumer finished reading the ring slot we reuse)
// Deps are acyclic in (it, w) and flags monotone -> deadlock-free.
// DEPTH=4 ring gives ~2 bodies of drift so wave phases stagger (pipe mixing).
// Recurrence fully in-register (kappa trick, verified r3-r7). FC fused.
__global__ __launch_bounds__(640, 1) void rnn_fused(
    const int* __restrict__ x, const float* __restrict__ emb,
    const float* __restrict__ W_ih, const float* __restrict__ W_hh,
    const float* __restrict__ b_ih, const float* __restrict__ b_hh,
    const float* __restrict__ W_fc, const float* __restrict__ b_fc,
    float* __restrict__ out)
{
    __shared__ __align__(16) unsigned char hb[DEPTH * (LAYERS - 1) * U * 1024]; // 144 KB
    __shared__ __align__(16) unsigned char fcs[1024];        // h_T frag for FC
    __shared__ volatile int prog[LAYERS * 16];               // flag per wave, 64B apart
    #define PROG(i) prog[(i) * 16]

    const int tid   = threadIdx.x;
    const int w     = tid >> 6;       // wave == layer
    const int lane  = tid & 63;
    const int bc    = lane & 15;      // batch col
    const int g     = lane >> 4;      // k-group / C row-group
    const int bbase = blockIdx.x * BPB;

    // zero h slots (insurance) + init flags
    for (int i = tid; i < (int)sizeof(hb) / 4; i += 640)
        ((unsigned*)hb)[i] = 0u;
    if (tid < LAYERS * 16) prog[tid] = 0;

    // ---- weight A-fragments (kappa-permuted cols; layer-0 W_ih natural)
    const float* ri0 = W_ih + (w * HIDDEN + bc)      * EMBED;
    const float* ri1 = W_ih + (w * HIDDEN + 16 + bc) * EMBED;
    const float* rh0 = W_hh + (w * HIDDEN + bc)      * HIDDEN;
    const float* rh1 = W_hh + (w * HIDDEN + 16 + bc) * HIDDEN;
    const uint4 wf00 = (w == 0) ? mk_nat(ri0, g) : mk_kp(ri0, g);
    const uint4 wf10 = (w == 0) ? mk_nat(ri1, g) : mk_kp(ri1, g);
    const uint4 wf01 = mk_kp(rh0, g);
    const uint4 wf11 = mk_kp(rh1, g);

    float bias2[8];
    #pragma unroll
    for (int m = 0; m < 2; ++m)
        #pragma unroll
        for (int r = 0; r < 4; ++r) {
            const int hid = w * HIDDEN + m * 16 + g * 4 + r;
            bias2[m * 4 + r] = 2.8853900817779268f * (b_ih[hid] + b_hh[hid]);
        }

    #define SL(s, l, u_) ((((s) * (LAYERS - 1) + (l)) * U + (u_)) * 1024)
    const int off = g * 256 + bc * 16;   // b128 frag address (write == read image)

    // ---- wave-0 feeder: cur = input frags for this body; tokens 1 body ahead
    uint4  cur[U];
    float4 eraw[U][2];
    int4   tok_pf;
    const int* xp = x + (bbase + bc) * SEQ;
    if (w == 0) {
        const int4 t4 = *(const int4*)(xp);                 // tokens t=0..3
        const int tk[U] = {t4.x, t4.y, t4.z, t4.w};
        #pragma unroll
        for (int u = 0; u < U; ++u) {
            const float4* ep = (const float4*)(emb + tk[u] * EMBED + g * 8);
            const float4 e0 = ep[0], e1 = ep[1];
            cur[u] = uint4{pk(e0.x, e0.y), pk(e0.z, e0.w), pk(e1.x, e1.y), pk(e1.z, e1.w)};
        }
        tok_pf = *(const int4*)(xp + U);                    // tokens t=4..7
    }

    uint4 bown = uint4{0, 0, 0, 0};   // own-h B-frag, register-resident forever
    const f32x4 z = {0.f, 0.f, 0.f, 0.f};

    __syncthreads();  // hb zeros + flag init visible; last barrier before epilogue

    auto body = [&](int it, int S) {   // S = it & 3 (literal per call site)
        const int tb = (it - w) * U;
        if (tb >= 0 && tb < SEQ) {
            // ---- spin-waits (broadcast ds_read, throttled)
            if (w > 0)
                while (PROG(w - 1) < it) __builtin_amdgcn_s_sleep(1);
            if (w < LAYERS - 1)
                while (PROG(w + 1) < it - 2) __builtin_amdgcn_s_sleep(1);
            asm volatile("" ::: "memory");

            // feeder: issue next-body emb gathers (latency spans this body)
            const bool pf = (w == 0) && (tb + U < SEQ);
            if (pf) {
                const int tk[U] = {tok_pf.x, tok_pf.y, tok_pf.z, tok_pf.w};
                #pragma unroll
                for (int u = 0; u < U; ++u) {
                    const float4* ep = (const float4*)(emb + tk[u] * EMBED + g * 8);
                    eraw[u][0] = ep[0]; eraw[u][1] = ep[1];
                }
                if (tb + 2 * U < SEQ)
                    tok_pf = *(const int4*)(xp + tb + 2 * U);
            }

            // input fragments (producer slot = body it-1 -> ring (S+3)&3)
            uint4 bin[U];
            if (w == 0) {
                #pragma unroll
                for (int u = 0; u < U; ++u) bin[u] = cur[u];
            } else {
                #pragma unroll
                for (int u = 0; u < U; ++u)
                    bin[u] = *(const uint4*)(hb + SL((S + 3) & 3, w - 1, u) + off);
            }
            f32x4 cin0[U], cin1[U];
            #pragma unroll
            for (int u = 0; u < U; ++u) {
                cin0[u] = __builtin_amdgcn_mfma_f32_16x16x32_f16(u2f(wf00), u2f(bin[u]), z, 0, 0, 0);
                cin1[u] = __builtin_amdgcn_mfma_f32_16x16x32_f16(u2f(wf10), u2f(bin[u]), z, 0, 0, 0);
            }

            // serial recurrence: mfma -> tanh -> pack IS the next B-frag
            #pragma unroll
            for (int u = 0; u < U; ++u) {
                const f32x4 c0 = __builtin_amdgcn_mfma_f32_16x16x32_f16(u2f(wf01), u2f(bown), cin0[u], 0, 0, 0);
                const f32x4 c1 = __builtin_amdgcn_mfma_f32_16x16x32_f16(u2f(wf11), u2f(bown), cin1[u], 0, 0, 0);

                float hv[8];
                #pragma unroll
                for (int r = 0; r < 4; ++r) {
                    hv[r]     = th(c0[r], bias2[r]);
                    hv[4 + r] = th(c1[r], bias2[4 + r]);
                }
                bown = uint4{pk(hv[0], hv[1]), pk(hv[2], hv[3]),
                             pk(hv[4], hv[5]), pk(hv[6], hv[7])};

                if (w < LAYERS - 1)   // handoff for next layer (one b128)
                    *(uint4*)(hb + SL(S, w, u) + off) = bown;
            }

            // order: hb writes complete -> flag bump (ds only; do NOT drain vmcnt)
            asm volatile("s_waitcnt lgkmcnt(0)" ::: "memory");
            if (lane == 0) PROG(w) = it + 1;

            if (pf) {   // pack next-body input frags (emb loads landed by now)
                #pragma unroll
                for (int u = 0; u < U; ++u) {
                    const float4 e0 = eraw[u][0], e1 = eraw[u][1];
                    cur[u] = uint4{pk(e0.x, e0.y), pk(e0.z, e0.w), pk(e1.x, e1.y), pk(e1.z, e1.w)};
                }
            }
        } else {
            if (lane == 0) PROG(w) = it + 1;   // inactive body: just advance
        }
    };

    for (int it = 0; it < NB; it += 4) {   // ring slot static per call site
        body(it + 0, 0);
        body(it + 1, 1);
        body(it + 2, 2);
        body(it + 3, 3);
    }
    #undef SL

    // ---- fused FC epilogue: out[b][v] = h_T . W_fc[v] + b_fc[v]
    if (w == LAYERS - 1) *(uint4*)(fcs + off) = bown;   // wave 9's bown == h_T frag
    __syncthreads();
    const uint4 bfc = *(const uint4*)(fcs + off);
    #pragma unroll
    for (int rep = 0; rep < 2; ++rep) {
        const int vt = w + rep * LAYERS;      // vocab tile 0..15
        if (vt < VOCABSZ / 16) {
            const uint4 afc = mk_kp(W_fc + (vt * 16 + bc) * HIDDEN, g);
            const f32x4 c = __builtin_amdgcn_mfma_f32_16x16x32_f16(u2f(afc), u2f(bfc), z, 0, 0, 0);
            const float4 b4 = *(const float4*)(b_fc + vt * 16 + 4 * g);
            const float4 o  = {c[0] + b4.x, c[1] + b4.y, c[2] + b4.z, c[3] + b4.w};
            *(float4*)(out + (bbase + bc) * VOCABSZ + vt * 16 + 4 * g) = o;
        }
    }
    #undef PROG
}

extern "C" void kernel_launch(void* const* d_in, const int* in_sizes, int n_in,
                              void* d_out, int out_size, void* d_ws, size_t ws_size,
                              hipStream_t stream) {
    const int*   x    = (const int*)d_in[0];
    const float* emb  = (const float*)d_in[1];
    const float* W_ih = (const float*)d_in[2];
    const float* W_hh = (const float*)d_in[3];
    const float* b_ih = (const float*)d_in[4];
    const float* b_hh = (const float*)d_in[5];
    const float* W_fc = (const float*)d_in[6];
    const float* b_fc = (const float*)d_in[7];
    float* out = (float*)d_out;

    rnn_fused<<<BATCH / BPB, 640, 0, stream>>>(x, emb, W_ih, W_hh, b_ih, b_hh,
                                               W_fc, b_fc, out);
}